// Round 10
// baseline (178.910 us; speedup 1.0000x reference)
//
#include <hip/hip_runtime.h>
#include <hip/hip_bf16.h>

#define NHEAD 12
#define TSEQ 2048
#define CEMB 768
#define DHEAD 64
#define NBATCH 4

typedef __attribute__((ext_vector_type(8))) short bf16x8;
typedef __attribute__((ext_vector_type(4))) float f32x4;

__device__ __forceinline__ ushort f2bf(float f) {
  union { float f; unsigned u; } v; v.f = f;
  unsigned u = v.u;
  u += 0x7FFFu + ((u >> 16) & 1u);   // RNE to bf16
  return (ushort)(u >> 16);
}

// packed f32x2 -> bf16x2 (1 inst, RNE) — T12 primitive
__device__ __forceinline__ unsigned cvt_pk_bf16(float lo, float hi) {
  unsigned r;
  asm("v_cvt_pk_bf16_f32 %0, %1, %2" : "=v"(r) : "v"(lo), "v"(hi));
  return r;
}

// raw v_exp_f32: D = 2^S0 (scores pre-scaled to log2 domain)
__device__ __forceinline__ float exp2_raw(float x) {
  float r;
  asm("v_exp_f32 %0, %1" : "=v"(r) : "v"(x));
  return r;
}

// wave-local LDS ordering (P buffer is wave-private; no block barrier needed)
__device__ __forceinline__ void lds_fence() {
  asm volatile("s_waitcnt lgkmcnt(0)" ::: "memory");
  __builtin_amdgcn_sched_barrier(0);   // rule 18
}

// ---------- fused prep: cast x -> bf16, transpose+cast Wa and Wo ----------
// blocks [0,3072): cast 8192x768 fp32->bf16 (2048 elems/block)
// blocks [3072, 3072+96*24): transpose tiles; bx<72 -> Wa [768][2304], else Wo [768][768]
__global__ __launch_bounds__(256)
void prep(const float* __restrict__ x, ushort* __restrict__ xb,
          const float* __restrict__ Wa, ushort* __restrict__ WaT,
          const float* __restrict__ Wo, ushort* __restrict__ WoT)
{
  __shared__ float tile[32][33];
  const int bid = blockIdx.x, t = threadIdx.x;
  if (bid < 3072) {
    int i = (bid * 256 + t) * 8;
    float4 v0 = *(const float4*)(x + i);
    float4 v1 = *(const float4*)(x + i + 4);
    bf16x8 wv;
    wv[0] = (short)f2bf(v0.x); wv[1] = (short)f2bf(v0.y);
    wv[2] = (short)f2bf(v0.z); wv[3] = (short)f2bf(v0.w);
    wv[4] = (short)f2bf(v1.x); wv[5] = (short)f2bf(v1.y);
    wv[6] = (short)f2bf(v1.z); wv[7] = (short)f2bf(v1.w);
    *(bf16x8*)(xb + i) = wv;
    return;
  }
  const int b2 = bid - 3072;
  const int bx = b2 % 96, by = b2 / 96;
  const int tx = t & 31, ty = t >> 5;         // (32,8)
  const float* src; ushort* dst; int C, c0;
  if (bx < 72) { src = Wa; dst = WaT; C = 3 * CEMB; c0 = bx * 32; }
  else         { src = Wo; dst = WoT; C = CEMB;     c0 = (bx - 72) * 32; }
  const int r0 = by * 32;
#pragma unroll
  for (int j = 0; j < 4; ++j)
    tile[ty + j * 8][tx] = src[(size_t)(r0 + ty + j * 8) * C + c0 + tx];
  __syncthreads();
#pragma unroll
  for (int j = 0; j < 4; ++j)
    dst[(size_t)(c0 + ty + j * 8) * CEMB + r0 + tx] = f2bf(tile[tx][ty + j * 8]);
}

// ---------- bf16 v [BH][T][D] -> vT [BH][D][T] ----------
__global__ void transpose_v(const ushort* __restrict__ src, ushort* __restrict__ dst) {
  __shared__ ushort tile[32][33];
  int bh = blockIdx.z;
  int t0 = blockIdx.x * 32, d0 = blockIdx.y * 32;
  int tx = threadIdx.x, ty = threadIdx.y;  // block (32,8)
  const ushort* s = src + (size_t)bh * TSEQ * DHEAD;
  ushort* o = dst + (size_t)bh * TSEQ * DHEAD;
#pragma unroll
  for (int j = 0; j < 4; ++j)
    tile[ty + j * 8][tx] = s[(t0 + ty + j * 8) * DHEAD + d0 + tx];
  __syncthreads();
#pragma unroll
  for (int j = 0; j < 4; ++j)
    o[(size_t)(d0 + ty + j * 8) * TSEQ + t0 + tx] = tile[tx][ty + j * 8];
}

// ---------- bf16 MFMA GEMM (m97 + 2-phase dbuf): C = A[M][K] * BT[N][K]^T + bias ----------
// Stage of tile kt+1 issued BEFORE computing tile kt (T3-minimum); one vmcnt(0)+barrier/iter.
// Slot-XOR swizzle s ^= (row>>1)&3 pre-applied on the GLOBAL source + same XOR on ds_read.
template<int EPI>
__global__ __launch_bounds__(256)
void gemm_bf16(const ushort* __restrict__ A, const ushort* __restrict__ BT,
               const float* __restrict__ bias, float* __restrict__ outF,
               ushort* __restrict__ qd, ushort* __restrict__ kd, ushort* __restrict__ vd,
               int M, int N, int K)
{
  __shared__ __align__(16) char smem[32768];   // buf p: As @ p*16384, Bs @ +8192
  const int t = threadIdx.x;
  const int lane = t & 63, wv = t >> 6;
  const int cc = lane & 15, gg = lane >> 4;
  const int m0 = blockIdx.y * 128, n0 = blockIdx.x * 128;
  const int wm = (wv >> 1) * 64, wn = (wv & 1) * 64;

  const int o0 = wv * 1024 + lane * 16;
  const int o1 = o0 + 4096;
  const int r0s = o0 >> 6, s0s = (o0 >> 4) & 3;
  const int r1s = o1 >> 6, s1s = (o1 >> 4) & 3;
  const size_t Kb = (size_t)K * 2;
  const char* a0p = (const char*)A  + (size_t)(m0 + r0s) * Kb + ((s0s ^ ((r0s >> 1) & 3)) << 4);
  const char* a1p = (const char*)A  + (size_t)(m0 + r1s) * Kb + ((s1s ^ ((r1s >> 1) & 3)) << 4);
  const char* b0p = (const char*)BT + (size_t)(n0 + r0s) * Kb + ((s0s ^ ((r0s >> 1) & 3)) << 4);
  const char* b1p = (const char*)BT + (size_t)(n0 + r1s) * Kb + ((s1s ^ ((r1s >> 1) & 3)) << 4);

  auto stage_g = [&](int p, int kb) {
    char* As = smem + p * 16384;
    char* Bs = As + 8192;
    __builtin_amdgcn_global_load_lds(
        (const __attribute__((address_space(1))) unsigned*)(a0p + kb),
        (__attribute__((address_space(3))) unsigned*)(As + wv * 1024), 16, 0, 0);
    __builtin_amdgcn_global_load_lds(
        (const __attribute__((address_space(1))) unsigned*)(a1p + kb),
        (__attribute__((address_space(3))) unsigned*)(As + wv * 1024 + 4096), 16, 0, 0);
    __builtin_amdgcn_global_load_lds(
        (const __attribute__((address_space(1))) unsigned*)(b0p + kb),
        (__attribute__((address_space(3))) unsigned*)(Bs + wv * 1024), 16, 0, 0);
    __builtin_amdgcn_global_load_lds(
        (const __attribute__((address_space(1))) unsigned*)(b1p + kb),
        (__attribute__((address_space(3))) unsigned*)(Bs + wv * 1024 + 4096), 16, 0, 0);
  };

  f32x4 acc[4][4];
#pragma unroll
  for (int i = 0; i < 4; ++i)
#pragma unroll
    for (int j = 0; j < 4; ++j) acc[i][j] = (f32x4){0.f, 0.f, 0.f, 0.f};

  const int KB = K * 2;
  stage_g(0, 0);
  asm volatile("s_waitcnt vmcnt(0)" ::: "memory");
  __syncthreads();
  int p = 0;
  for (int kb = 0; kb < KB; kb += 64) {
    if (kb + 64 < KB) stage_g(p ^ 1, kb + 64);   // prefetch next tile (overlaps compute)
    const char* As = smem + p * 16384;
    const char* Bs = As + 8192;
    bf16x8 fa[4], fb[4];
#pragma unroll
    for (int i = 0; i < 4; ++i) {
      const int r = wm + i * 16 + cc;
      fa[i] = *(const bf16x8*)(As + r * 64 + ((gg ^ ((r >> 1) & 3)) << 4));
    }
#pragma unroll
    for (int j = 0; j < 4; ++j) {
      const int r = wn + j * 16 + cc;
      fb[j] = *(const bf16x8*)(Bs + r * 64 + ((gg ^ ((r >> 1) & 3)) << 4));
    }
    __builtin_amdgcn_s_setprio(1);
#pragma unroll
    for (int i = 0; i < 4; ++i)
#pragma unroll
      for (int j = 0; j < 4; ++j)
        acc[i][j] = __builtin_amdgcn_mfma_f32_16x16x32_bf16(fa[i], fb[j], acc[i][j], 0, 0, 0);
    __builtin_amdgcn_s_setprio(0);
    asm volatile("s_waitcnt vmcnt(0)" ::: "memory");   // next tile's stage landed
    __syncthreads();                                   // all waves done reading buf p
    p ^= 1;
  }

#pragma unroll
  for (int i = 0; i < 4; ++i) {
#pragma unroll
    for (int j = 0; j < 4; ++j) {
      int gm0 = m0 + wm + i * 16 + gg * 4;
      int gn  = n0 + wn + j * 16 + cc;
      float bv = bias[gn];
      if (EPI == 0) {
#pragma unroll
        for (int e = 0; e < 4; ++e)
          outF[(size_t)(gm0 + e) * N + gn] = acc[i][j][e] + bv;
      } else {
        int which = gn / CEMB;
        int r = gn - which * CEMB;
        int hh = r >> 6, dd = r & 63;
        ushort* dst = which == 0 ? qd : (which == 1 ? kd : vd);
        // q scale: 1/sqrt(D) * log2(e) — softmax computed with exp2
        float sc = (which == 0) ? 0.125f * 1.4426950408889634f : 1.0f;
#pragma unroll
        for (int e = 0; e < 4; ++e) {
          int gm = gm0 + e;
          int tt = gm & (TSEQ - 1), bb = gm >> 11;
          dst[(size_t)((bb * NHEAD + hh) * TSEQ + tt) * DHEAD + dd] = f2bf((acc[i][j][e] + bv) * sc);
        }
      }
    }
  }
}

// ---------- flash attention (R8 structure; K LDS-staged dbuf, V direct from XCD-local L2) ----------
// 1-D grid 768; decode maps all 16 bx-blocks of a head to ONE XCD (T1: K/V L2-resident).
// Block bx handles q-tiles bx and NT-1-bx (balanced, NT+1 key-tiles/wave).
// K staged via global_load_lds (rule-21 pre-swizzled source, XOR (row&7)<<4); V fragments
// loaded directly from global vT (early-issued after QK^T; L2 hit, latency hidden by softmax)
// — V-staging dropped since T1 made V XCD-L2-resident (m214 lesson 7). LDS 24576 B.
// Softmax in exp2 domain (Q pre-scaled by log2e/8), defer-max THR = 8*log2e.
__global__ __launch_bounds__(256)
void attn_fwd(const ushort* __restrict__ qg, const ushort* __restrict__ kg,
              const ushort* __restrict__ vTg, ushort* __restrict__ ybb)
{
  // LDS: K[2] @ 0 (2 x 8KB, swizzled), P @ 16384 (4 waves x 2KB)
  __shared__ __align__(16) char smem[24576];
  const int t = threadIdx.x, lane = t & 63, w = t >> 6;
  const int cc = lane & 15, gg = lane >> 4;
  const int NT = TSEQ / 64;
  const int L = blockIdx.x;
  const int r9 = L >> 3;
  const int bx = r9 & 15;
  const int bh = (L & 7) + 8 * (r9 >> 4);     // same bh -> same XCD slot
  const int b = bh / NHEAD, h = bh - b * NHEAD;

  const char* Kg = (const char*)(kg + (size_t)bh * TSEQ * DHEAD);   // [T][64], 128B rows
  const ushort* Vg = vTg + (size_t)bh * TSEQ * DHEAD;               // [64][T]

  const int srow = lane >> 3;                        // row&7 within 8-row chunk
  const int ssw  = ((lane & 7) * 16) ^ (srow << 4);  // pre-swizzled source colbyte

  ushort* Pw = (ushort*)(smem + 16384 + w * 2048);   // wave-private [16][64], swizzled
  const int sw8 = (cc & 7) << 3;

  auto stage = [&](int pp, int kt) {
#pragma unroll
    for (int i = 0; i < 2; ++i) {
      const int c = w * 2 + i;
      const char* gk = Kg + (size_t)(kt * 64 + c * 8 + srow) * 128 + ssw;
      __builtin_amdgcn_global_load_lds(
          (const __attribute__((address_space(1))) unsigned*)gk,
          (__attribute__((address_space(3))) unsigned*)(smem + pp * 8192 + c * 1024),
          16, 0, 0);
    }
  };

  int p = 0;
  for (int pass = 0; pass < 2; ++pass) {
    const int qt = pass ? (NT - 1 - bx) : bx;
    const int qrow0 = qt * 64 + w * 16;

    const ushort* Qp = qg + ((size_t)bh * TSEQ + qrow0) * DHEAD;
    bf16x8 fq0 = *(const bf16x8*)(Qp + cc * DHEAD + 8 * gg);
    bf16x8 fq1 = *(const bf16x8*)(Qp + cc * DHEAD + 32 + 8 * gg);

    f32x4 o[4];   // O^T: o[dt][e] = O^T[d = dt*16 + gg*4 + e, q = cc]
#pragma unroll
    for (int i = 0; i < 4; ++i) o[i] = (f32x4){0.f, 0.f, 0.f, 0.f};
    float m = -1e30f, l = 0.f;

    stage(p, 0);
    asm volatile("s_waitcnt vmcnt(0)" ::: "memory");
    __syncthreads();

    for (int kt = 0; kt <= qt; ++kt) {
      if (kt < qt) stage(p ^ 1, kt + 1);   // prefetch next K tile

      const char* Kl = smem + p * 8192;
      f32x4 st[4];   // st[ct][e] = S^T[key = 16ct + 4gg + e, q = cc]  (log2 domain)
#pragma unroll
      for (int ct = 0; ct < 4; ++ct) st[ct] = (f32x4){0.f, 0.f, 0.f, 0.f};
      __builtin_amdgcn_s_setprio(1);
#pragma unroll
      for (int ct = 0; ct < 4; ++ct) {
        const int r = ct * 16 + cc;
        const char* kb = Kl + r * 128;
        bf16x8 fk0 = *(const bf16x8*)(kb + ((gg * 16) ^ ((r & 7) << 4)));
        bf16x8 fk1 = *(const bf16x8*)(kb + ((64 + gg * 16) ^ ((r & 7) << 4)));
        st[ct] = __builtin_amdgcn_mfma_f32_16x16x32_bf16(fk0, fq0, st[ct], 0, 0, 0);
        st[ct] = __builtin_amdgcn_mfma_f32_16x16x32_bf16(fk1, fq1, st[ct], 0, 0, 0);
      }
      __builtin_amdgcn_s_setprio(0);

      // early-issue V fragment loads (global vT, XCD-L2 hit); latency hides under softmax
      const ushort* Vp = Vg + kt * 64;
      bf16x8 fv[4][2];
#pragma unroll
      for (int dt = 0; dt < 4; ++dt)
#pragma unroll
        for (int kc = 0; kc < 2; ++kc)
          fv[dt][kc] = *(const bf16x8*)(Vp + (size_t)(dt * 16 + cc) * TSEQ + kc * 32 + 8 * gg);

      if (kt == qt) {   // causal mask on the diagonal tile
#pragma unroll
        for (int ct = 0; ct < 4; ++ct)
#pragma unroll
          for (int e = 0; e < 4; ++e)
            if (ct * 16 + gg * 4 + e > w * 16 + cc) st[ct][e] = -1e30f;
      }
      float ml = st[0][0];
#pragma unroll
      for (int ct = 0; ct < 4; ++ct)
#pragma unroll
        for (int e = 0; e < 4; ++e) ml = fmaxf(ml, st[ct][e]);
      ml = fmaxf(ml, __shfl_xor(ml, 16, 64));
      ml = fmaxf(ml, __shfl_xor(ml, 32, 64));
      float mn = m;
      if (!__all(ml - m <= 11.54f)) {   // defer-max (T13), THR = 8*log2e
        mn = fmaxf(m, ml);
        float al = exp2_raw(m - mn);
#pragma unroll
        for (int dt = 0; dt < 4; ++dt)
#pragma unroll
          for (int e = 0; e < 4; ++e) o[dt][e] *= al;
        l *= al;
        m = mn;
      }
      float ps = 0.f;
#pragma unroll
      for (int ct = 0; ct < 4; ++ct)
#pragma unroll
        for (int e = 0; e < 4; ++e) { float pp = exp2_raw(st[ct][e] - mn); st[ct][e] = pp; ps += pp; }
#pragma unroll
      for (int ct = 0; ct < 4; ++ct) {
        uint2 pw;
        pw.x = cvt_pk_bf16(st[ct][0], st[ct][1]);
        pw.y = cvt_pk_bf16(st[ct][2], st[ct][3]);
        *(uint2*)&Pw[cc * 64 + ((ct * 16 + gg * 4) ^ sw8)] = pw;
      }
      ps += __shfl_xor(ps, 16, 64);
      ps += __shfl_xor(ps, 32, 64);
      l += ps;
      lds_fence();   // wave-local: P writes complete before fragment reads
      __builtin_amdgcn_s_setprio(1);
#pragma unroll
      for (int kc = 0; kc < 2; ++kc) {
        bf16x8 pb = *(const bf16x8*)&Pw[cc * 64 + ((kc * 32 + 8 * gg) ^ sw8)];
#pragma unroll
        for (int dt = 0; dt < 4; ++dt)
          o[dt] = __builtin_amdgcn_mfma_f32_16x16x32_bf16(fv[dt][kc], pb, o[dt], 0, 0, 0);
      }
      __builtin_amdgcn_s_setprio(0);
      asm volatile("s_waitcnt vmcnt(0)" ::: "memory");   // next K stage landed
      __syncthreads();                                   // all waves done with buf p
      p ^= 1;
    }

    float inv = 1.0f / l;
    ushort* yrow = ybb + (size_t)(b * TSEQ + qrow0 + cc) * CEMB + h * DHEAD;
#pragma unroll
    for (int dt = 0; dt < 4; ++dt) {
      uint2 pw;
      pw.x = cvt_pk_bf16(o[dt][0] * inv, o[dt][1] * inv);
      pw.y = cvt_pk_bf16(o[dt][2] * inv, o[dt][3] * inv);
      *(uint2*)(yrow + dt * 16 + gg * 4) = pw;
    }
  }
}

extern "C" void kernel_launch(void* const* d_in, const int* in_sizes, int n_in,
                              void* d_out, int out_size, void* d_ws, size_t ws_size,
                              hipStream_t stream)
{
  (void)in_sizes; (void)n_in; (void)out_size; (void)ws_size;
  const float* x  = (const float*)d_in[0];
  const float* Wa = (const float*)d_in[1];
  const float* ba = (const float*)d_in[2];
  const float* Wo = (const float*)d_in[3];
  const float* bo = (const float*)d_in[4];
  float* out = (float*)d_out;

  char* p = (char*)d_ws;
  ushort* WaT  = (ushort*)p; p += (size_t)3 * CEMB * CEMB * 2;               // [2304][768] bf16
  ushort* WoT  = (ushort*)p; p += (size_t)CEMB * CEMB * 2;                   // [768][768] bf16
  ushort* xb   = (ushort*)p; p += (size_t)NBATCH * TSEQ * CEMB * 2;          // x bf16 [B*T][C]
  ushort* qb   = (ushort*)p; p += (size_t)NBATCH * NHEAD * TSEQ * DHEAD * 2; // [B,H,T,D]
  ushort* kb   = (ushort*)p; p += (size_t)NBATCH * NHEAD * TSEQ * DHEAD * 2;
  ushort* vtmp = (ushort*)p; p += (size_t)NBATCH * NHEAD * TSEQ * DHEAD * 2;
  ushort* vT   = (ushort*)p; p += (size_t)NBATCH * NHEAD * TSEQ * DHEAD * 2; // [B,H,D,T]
  ushort* yb   = (ushort*)p; p += (size_t)NBATCH * TSEQ * CEMB * 2;          // attn out bf16

  prep<<<3072 + 96 * 24, 256, 0, stream>>>(x, xb, Wa, WaT, Wo, WoT);
  gemm_bf16<1><<<dim3(3 * CEMB / 128, NBATCH * TSEQ / 128), 256, 0, stream>>>(
      xb, WaT, ba, nullptr, qb, kb, vtmp, NBATCH * TSEQ, 3 * CEMB, CEMB);
  transpose_v<<<dim3(TSEQ / 32, DHEAD / 32, NBATCH * NHEAD), dim3(32, 8), 0, stream>>>(vtmp, vT);
  attn_fwd<<<dim3(TSEQ / 128 * NBATCH * NHEAD), 256, 0, stream>>>(qb, kb, vT, yb);
  gemm_bf16<0><<<dim3(CEMB / 128, NBATCH * TSEQ / 128), 256, 0, stream>>>(
      yb, WoT, bo, out, nullptr, nullptr, nullptr, NBATCH * TSEQ, CEMB, CEMB);
}

// Round 11
// 133.664 us; speedup vs baseline: 1.3385x; 1.3385x over previous
//
#include <hip/hip_runtime.h>
#include <hip/hip_bf16.h>

#define NHEAD 12
#define TSEQ 2048
#define CEMB 768
#define DHEAD 64
#define NBATCH 4

typedef __attribute__((ext_vector_type(8))) short bf16x8;
typedef __attribute__((ext_vector_type(4))) float f32x4;

__device__ __forceinline__ ushort f2bf(float f) {
  union { float f; unsigned u; } v; v.f = f;
  unsigned u = v.u;
  u += 0x7FFFu + ((u >> 16) & 1u);   // RNE to bf16
  return (ushort)(u >> 16);
}

// packed f32x2 -> bf16x2 (1 inst, RNE) — T12 primitive
__device__ __forceinline__ unsigned cvt_pk_bf16(float lo, float hi) {
  unsigned r;
  asm("v_cvt_pk_bf16_f32 %0, %1, %2" : "=v"(r) : "v"(lo), "v"(hi));
  return r;
}

// raw v_exp_f32: D = 2^S0 (scores pre-scaled to log2 domain)
__device__ __forceinline__ float exp2_raw(float x) {
  float r;
  asm("v_exp_f32 %0, %1" : "=v"(r) : "v"(x));
  return r;
}

// wave-local LDS ordering (P buffer is wave-private; no block barrier needed)
__device__ __forceinline__ void lds_fence() {
  asm volatile("s_waitcnt lgkmcnt(0)" ::: "memory");
  __builtin_amdgcn_sched_barrier(0);   // rule 18
}

// ---------- fused prep: cast x -> bf16, transpose+cast Wa and Wo ----------
__global__ __launch_bounds__(256)
void prep(const float* __restrict__ x, ushort* __restrict__ xb,
          const float* __restrict__ Wa, ushort* __restrict__ WaT,
          const float* __restrict__ Wo, ushort* __restrict__ WoT)
{
  __shared__ float tile[32][33];
  const int bid = blockIdx.x, t = threadIdx.x;
  if (bid < 3072) {
    int i = (bid * 256 + t) * 8;
    float4 v0 = *(const float4*)(x + i);
    float4 v1 = *(const float4*)(x + i + 4);
    bf16x8 wv;
    wv[0] = (short)f2bf(v0.x); wv[1] = (short)f2bf(v0.y);
    wv[2] = (short)f2bf(v0.z); wv[3] = (short)f2bf(v0.w);
    wv[4] = (short)f2bf(v1.x); wv[5] = (short)f2bf(v1.y);
    wv[6] = (short)f2bf(v1.z); wv[7] = (short)f2bf(v1.w);
    *(bf16x8*)(xb + i) = wv;
    return;
  }
  const int b2 = bid - 3072;
  const int bx = b2 % 96, by = b2 / 96;
  const int tx = t & 31, ty = t >> 5;         // (32,8)
  const float* src; ushort* dst; int C, c0;
  if (bx < 72) { src = Wa; dst = WaT; C = 3 * CEMB; c0 = bx * 32; }
  else         { src = Wo; dst = WoT; C = CEMB;     c0 = (bx - 72) * 32; }
  const int r0 = by * 32;
#pragma unroll
  for (int j = 0; j < 4; ++j)
    tile[ty + j * 8][tx] = src[(size_t)(r0 + ty + j * 8) * C + c0 + tx];
  __syncthreads();
#pragma unroll
  for (int j = 0; j < 4; ++j)
    dst[(size_t)(c0 + ty + j * 8) * CEMB + r0 + tx] = f2bf(tile[tx][ty + j * 8]);
}

// ---------- bf16 v [BH][T][D] -> vT [BH][D][T] ----------
__global__ void transpose_v(const ushort* __restrict__ src, ushort* __restrict__ dst) {
  __shared__ ushort tile[32][33];
  int bh = blockIdx.z;
  int t0 = blockIdx.x * 32, d0 = blockIdx.y * 32;
  int tx = threadIdx.x, ty = threadIdx.y;  // block (32,8)
  const ushort* s = src + (size_t)bh * TSEQ * DHEAD;
  ushort* o = dst + (size_t)bh * TSEQ * DHEAD;
#pragma unroll
  for (int j = 0; j < 4; ++j)
    tile[ty + j * 8][tx] = s[(t0 + ty + j * 8) * DHEAD + d0 + tx];
  __syncthreads();
#pragma unroll
  for (int j = 0; j < 4; ++j)
    o[(size_t)(d0 + ty + j * 8) * TSEQ + t0 + tx] = tile[tx][ty + j * 8];
}

// ---------- bf16 MFMA GEMM (m97 + 2-phase dbuf): C = A[M][K] * BT[N][K]^T + bias ----------
template<int EPI>
__global__ __launch_bounds__(256)
void gemm_bf16(const ushort* __restrict__ A, const ushort* __restrict__ BT,
               const float* __restrict__ bias, float* __restrict__ outF,
               ushort* __restrict__ qd, ushort* __restrict__ kd, ushort* __restrict__ vd,
               int M, int N, int K)
{
  __shared__ __align__(16) char smem[32768];   // buf p: As @ p*16384, Bs @ +8192
  const int t = threadIdx.x;
  const int lane = t & 63, wv = t >> 6;
  const int cc = lane & 15, gg = lane >> 4;
  const int m0 = blockIdx.y * 128, n0 = blockIdx.x * 128;
  const int wm = (wv >> 1) * 64, wn = (wv & 1) * 64;

  const int o0 = wv * 1024 + lane * 16;
  const int o1 = o0 + 4096;
  const int r0s = o0 >> 6, s0s = (o0 >> 4) & 3;
  const int r1s = o1 >> 6, s1s = (o1 >> 4) & 3;
  const size_t Kb = (size_t)K * 2;
  const char* a0p = (const char*)A  + (size_t)(m0 + r0s) * Kb + ((s0s ^ ((r0s >> 1) & 3)) << 4);
  const char* a1p = (const char*)A  + (size_t)(m0 + r1s) * Kb + ((s1s ^ ((r1s >> 1) & 3)) << 4);
  const char* b0p = (const char*)BT + (size_t)(n0 + r0s) * Kb + ((s0s ^ ((r0s >> 1) & 3)) << 4);
  const char* b1p = (const char*)BT + (size_t)(n0 + r1s) * Kb + ((s1s ^ ((r1s >> 1) & 3)) << 4);

  auto stage_g = [&](int p, int kb) {
    char* As = smem + p * 16384;
    char* Bs = As + 8192;
    __builtin_amdgcn_global_load_lds(
        (const __attribute__((address_space(1))) unsigned*)(a0p + kb),
        (__attribute__((address_space(3))) unsigned*)(As + wv * 1024), 16, 0, 0);
    __builtin_amdgcn_global_load_lds(
        (const __attribute__((address_space(1))) unsigned*)(a1p + kb),
        (__attribute__((address_space(3))) unsigned*)(As + wv * 1024 + 4096), 16, 0, 0);
    __builtin_amdgcn_global_load_lds(
        (const __attribute__((address_space(1))) unsigned*)(b0p + kb),
        (__attribute__((address_space(3))) unsigned*)(Bs + wv * 1024), 16, 0, 0);
    __builtin_amdgcn_global_load_lds(
        (const __attribute__((address_space(1))) unsigned*)(b1p + kb),
        (__attribute__((address_space(3))) unsigned*)(Bs + wv * 1024 + 4096), 16, 0, 0);
  };

  f32x4 acc[4][4];
#pragma unroll
  for (int i = 0; i < 4; ++i)
#pragma unroll
    for (int j = 0; j < 4; ++j) acc[i][j] = (f32x4){0.f, 0.f, 0.f, 0.f};

  const int KB = K * 2;
  stage_g(0, 0);
  asm volatile("s_waitcnt vmcnt(0)" ::: "memory");
  __syncthreads();
  int p = 0;
  for (int kb = 0; kb < KB; kb += 64) {
    if (kb + 64 < KB) stage_g(p ^ 1, kb + 64);   // prefetch next tile (overlaps compute)
    const char* As = smem + p * 16384;
    const char* Bs = As + 8192;
    bf16x8 fa[4], fb[4];
#pragma unroll
    for (int i = 0; i < 4; ++i) {
      const int r = wm + i * 16 + cc;
      fa[i] = *(const bf16x8*)(As + r * 64 + ((gg ^ ((r >> 1) & 3)) << 4));
    }
#pragma unroll
    for (int j = 0; j < 4; ++j) {
      const int r = wn + j * 16 + cc;
      fb[j] = *(const bf16x8*)(Bs + r * 64 + ((gg ^ ((r >> 1) & 3)) << 4));
    }
    __builtin_amdgcn_s_setprio(1);
#pragma unroll
    for (int i = 0; i < 4; ++i)
#pragma unroll
      for (int j = 0; j < 4; ++j)
        acc[i][j] = __builtin_amdgcn_mfma_f32_16x16x32_bf16(fa[i], fb[j], acc[i][j], 0, 0, 0);
    __builtin_amdgcn_s_setprio(0);
    asm volatile("s_waitcnt vmcnt(0)" ::: "memory");   // next tile's stage landed
    __syncthreads();                                   // all waves done reading buf p
    p ^= 1;
  }

#pragma unroll
  for (int i = 0; i < 4; ++i) {
#pragma unroll
    for (int j = 0; j < 4; ++j) {
      int gm0 = m0 + wm + i * 16 + gg * 4;
      int gn  = n0 + wn + j * 16 + cc;
      float bv = bias[gn];
      if (EPI == 0) {
#pragma unroll
        for (int e = 0; e < 4; ++e)
          outF[(size_t)(gm0 + e) * N + gn] = acc[i][j][e] + bv;
      } else {
        int which = gn / CEMB;
        int r = gn - which * CEMB;
        int hh = r >> 6, dd = r & 63;
        ushort* dst = which == 0 ? qd : (which == 1 ? kd : vd);
        // q scale: 1/sqrt(D) * log2(e) — softmax computed with exp2
        float sc = (which == 0) ? 0.125f * 1.4426950408889634f : 1.0f;
#pragma unroll
        for (int e = 0; e < 4; ++e) {
          int gm = gm0 + e;
          int tt = gm & (TSEQ - 1), bb = gm >> 11;
          dst[(size_t)((bb * NHEAD + hh) * TSEQ + tt) * DHEAD + dd] = f2bf((acc[i][j][e] + bv) * sc);
        }
      }
    }
  }
}

// ---------- flash attention (R8-proven: K AND V LDS-staged dbuf, swizzled, XCD-grouped) ----------
// 1-D grid 768; decode maps all 16 bx-blocks of a head onto ONE XCD (T1).
// Block bx handles q-tiles bx and NT-1-bx (balanced, NT+1 key-tiles/wave).
// K/V staged per block via global_load_lds (rule-21 pre-swizzled source, XOR (row&7)<<4)
// — NOTE (R10 lesson): direct global V reads regress 1.8x despite L2 residency; the
// vT access is a 16-row scatter per instruction, only LDS staging keeps it coalesced.
// P: wave-private [16][64] ushort, XOR-swizzled. LDS 40960 B.
// Softmax in exp2 domain (Q pre-scaled by log2e/8), defer-max THR = 8*log2e.
__global__ __launch_bounds__(256)
void attn_fwd(const ushort* __restrict__ qg, const ushort* __restrict__ kg,
              const ushort* __restrict__ vTg, ushort* __restrict__ ybb)
{
  // LDS: K[2] @ 0 (2 x 8KB, swizzled), V[2] @ 16384, P @ 32768 (4 waves x 2KB)
  __shared__ __align__(16) char smem[40960];
  const int t = threadIdx.x, lane = t & 63, w = t >> 6;
  const int cc = lane & 15, gg = lane >> 4;
  const int NT = TSEQ / 64;
  const int L = blockIdx.x;
  const int r9 = L >> 3;
  const int bx = r9 & 15;
  const int bh = (L & 7) + 8 * (r9 >> 4);     // same bh -> same XCD slot
  const int b = bh / NHEAD, h = bh - b * NHEAD;

  const char* Kg = (const char*)(kg + (size_t)bh * TSEQ * DHEAD);   // [T][64], 128B rows
  const char* Vg = (const char*)(vTg + (size_t)bh * TSEQ * DHEAD);  // [64][T], 4096B rows

  const int srow = lane >> 3;                        // row&7 within 8-row chunk
  const int ssw  = ((lane & 7) * 16) ^ (srow << 4);  // pre-swizzled source colbyte

  ushort* Pw = (ushort*)(smem + 32768 + w * 2048);   // wave-private [16][64], swizzled
  const int sw8 = (cc & 7) << 3;

  auto stage = [&](int pp, int kt) {
#pragma unroll
    for (int i = 0; i < 2; ++i) {
      const int c = w * 2 + i;
      const char* gk = Kg + (size_t)(kt * 64 + c * 8 + srow) * 128 + ssw;
      __builtin_amdgcn_global_load_lds(
          (const __attribute__((address_space(1))) unsigned*)gk,
          (__attribute__((address_space(3))) unsigned*)(smem + pp * 8192 + c * 1024),
          16, 0, 0);
      const char* gv = Vg + (size_t)(c * 8 + srow) * (TSEQ * 2) + (size_t)kt * 128 + ssw;
      __builtin_amdgcn_global_load_lds(
          (const __attribute__((address_space(1))) unsigned*)gv,
          (__attribute__((address_space(3))) unsigned*)(smem + 16384 + pp * 8192 + c * 1024),
          16, 0, 0);
    }
  };

  int p = 0;
  for (int pass = 0; pass < 2; ++pass) {
    const int qt = pass ? (NT - 1 - bx) : bx;
    const int qrow0 = qt * 64 + w * 16;

    const ushort* Qp = qg + ((size_t)bh * TSEQ + qrow0) * DHEAD;
    bf16x8 fq0 = *(const bf16x8*)(Qp + cc * DHEAD + 8 * gg);
    bf16x8 fq1 = *(const bf16x8*)(Qp + cc * DHEAD + 32 + 8 * gg);

    f32x4 o[4];   // O^T: o[dt][e] = O^T[d = dt*16 + gg*4 + e, q = cc]
#pragma unroll
    for (int i = 0; i < 4; ++i) o[i] = (f32x4){0.f, 0.f, 0.f, 0.f};
    float m = -1e30f, l = 0.f;

    stage(p, 0);
    asm volatile("s_waitcnt vmcnt(0)" ::: "memory");
    __syncthreads();

    for (int kt = 0; kt <= qt; ++kt) {
      if (kt < qt) stage(p ^ 1, kt + 1);   // prefetch next tile

      const char* Kl = smem + p * 8192;
      const char* Vl = smem + 16384 + p * 8192;
      f32x4 st[4];   // st[ct][e] = S^T[key = 16ct + 4gg + e, q = cc]  (log2 domain)
#pragma unroll
      for (int ct = 0; ct < 4; ++ct) st[ct] = (f32x4){0.f, 0.f, 0.f, 0.f};
      __builtin_amdgcn_s_setprio(1);
#pragma unroll
      for (int ct = 0; ct < 4; ++ct) {
        const int r = ct * 16 + cc;
        const char* kb = Kl + r * 128;
        bf16x8 fk0 = *(const bf16x8*)(kb + ((gg * 16) ^ ((r & 7) << 4)));
        bf16x8 fk1 = *(const bf16x8*)(kb + ((64 + gg * 16) ^ ((r & 7) << 4)));
        st[ct] = __builtin_amdgcn_mfma_f32_16x16x32_bf16(fk0, fq0, st[ct], 0, 0, 0);
        st[ct] = __builtin_amdgcn_mfma_f32_16x16x32_bf16(fk1, fq1, st[ct], 0, 0, 0);
      }
      __builtin_amdgcn_s_setprio(0);

      if (kt == qt) {   // causal mask on the diagonal tile
#pragma unroll
        for (int ct = 0; ct < 4; ++ct)
#pragma unroll
          for (int e = 0; e < 4; ++e)
            if (ct * 16 + gg * 4 + e > w * 16 + cc) st[ct][e] = -1e30f;
      }
      float ml = st[0][0];
#pragma unroll
      for (int ct = 0; ct < 4; ++ct)
#pragma unroll
        for (int e = 0; e < 4; ++e) ml = fmaxf(ml, st[ct][e]);
      ml = fmaxf(ml, __shfl_xor(ml, 16, 64));
      ml = fmaxf(ml, __shfl_xor(ml, 32, 64));
      float mn = m;
      if (!__all(ml - m <= 11.54f)) {   // defer-max (T13), THR = 8*log2e
        mn = fmaxf(m, ml);
        float al = exp2_raw(m - mn);
#pragma unroll
        for (int dt = 0; dt < 4; ++dt)
#pragma unroll
          for (int e = 0; e < 4; ++e) o[dt][e] *= al;
        l *= al;
        m = mn;
      }
      float ps = 0.f;
#pragma unroll
      for (int ct = 0; ct < 4; ++ct)
#pragma unroll
        for (int e = 0; e < 4; ++e) { float pp = exp2_raw(st[ct][e] - mn); st[ct][e] = pp; ps += pp; }
#pragma unroll
      for (int ct = 0; ct < 4; ++ct) {
        uint2 pw;
        pw.x = cvt_pk_bf16(st[ct][0], st[ct][1]);
        pw.y = cvt_pk_bf16(st[ct][2], st[ct][3]);
        *(uint2*)&Pw[cc * 64 + ((ct * 16 + gg * 4) ^ sw8)] = pw;
      }
      ps += __shfl_xor(ps, 16, 64);
      ps += __shfl_xor(ps, 32, 64);
      l += ps;
      lds_fence();   // wave-local: P writes complete before fragment reads
      __builtin_amdgcn_s_setprio(1);
#pragma unroll
      for (int kc = 0; kc < 2; ++kc) {
        bf16x8 pb = *(const bf16x8*)&Pw[cc * 64 + ((kc * 32 + 8 * gg) ^ sw8)];
#pragma unroll
        for (int dt = 0; dt < 4; ++dt) {
          const int rd = dt * 16 + cc;
          bf16x8 fv = *(const bf16x8*)(Vl + rd * 128 + ((kc * 64 + gg * 16) ^ ((rd & 7) << 4)));
          o[dt] = __builtin_amdgcn_mfma_f32_16x16x32_bf16(fv, pb, o[dt], 0, 0, 0);
        }
      }
      __builtin_amdgcn_s_setprio(0);
      asm volatile("s_waitcnt vmcnt(0)" ::: "memory");   // next tile's stage landed
      __syncthreads();                                   // all waves done with buf p
      p ^= 1;
    }

    float inv = 1.0f / l;
    ushort* yrow = ybb + (size_t)(b * TSEQ + qrow0 + cc) * CEMB + h * DHEAD;
#pragma unroll
    for (int dt = 0; dt < 4; ++dt) {
      uint2 pw;
      pw.x = cvt_pk_bf16(o[dt][0] * inv, o[dt][1] * inv);
      pw.y = cvt_pk_bf16(o[dt][2] * inv, o[dt][3] * inv);
      *(uint2*)(yrow + dt * 16 + gg * 4) = pw;
    }
  }
}

extern "C" void kernel_launch(void* const* d_in, const int* in_sizes, int n_in,
                              void* d_out, int out_size, void* d_ws, size_t ws_size,
                              hipStream_t stream)
{
  (void)in_sizes; (void)n_in; (void)out_size; (void)ws_size;
  const float* x  = (const float*)d_in[0];
  const float* Wa = (const float*)d_in[1];
  const float* ba = (const float*)d_in[2];
  const float* Wo = (const float*)d_in[3];
  const float* bo = (const float*)d_in[4];
  float* out = (float*)d_out;

  char* p = (char*)d_ws;
  ushort* WaT  = (ushort*)p; p += (size_t)3 * CEMB * CEMB * 2;               // [2304][768] bf16
  ushort* WoT  = (ushort*)p; p += (size_t)CEMB * CEMB * 2;                   // [768][768] bf16
  ushort* xb   = (ushort*)p; p += (size_t)NBATCH * TSEQ * CEMB * 2;          // x bf16 [B*T][C]
  ushort* qb   = (ushort*)p; p += (size_t)NBATCH * NHEAD * TSEQ * DHEAD * 2; // [B,H,T,D]
  ushort* kb   = (ushort*)p; p += (size_t)NBATCH * NHEAD * TSEQ * DHEAD * 2;
  ushort* vtmp = (ushort*)p; p += (size_t)NBATCH * NHEAD * TSEQ * DHEAD * 2;
  ushort* vT   = (ushort*)p; p += (size_t)NBATCH * NHEAD * TSEQ * DHEAD * 2; // [B,H,D,T]
  ushort* yb   = (ushort*)p; p += (size_t)NBATCH * TSEQ * CEMB * 2;          // attn out bf16

  prep<<<3072 + 96 * 24, 256, 0, stream>>>(x, xb, Wa, WaT, Wo, WoT);
  gemm_bf16<1><<<dim3(3 * CEMB / 128, NBATCH * TSEQ / 128), 256, 0, stream>>>(
      xb, WaT, ba, nullptr, qb, kb, vtmp, NBATCH * TSEQ, 3 * CEMB, CEMB);
  transpose_v<<<dim3(TSEQ / 32, DHEAD / 32, NBATCH * NHEAD), dim3(32, 8), 0, stream>>>(vtmp, vT);
  attn_fwd<<<dim3(TSEQ / 128 * NBATCH * NHEAD), 256, 0, stream>>>(qb, kb, vT, yb);
  gemm_bf16<0><<<dim3(CEMB / 128, NBATCH * TSEQ / 128), 256, 0, stream>>>(
      yb, WoT, bo, out, nullptr, nullptr, nullptr, NBATCH * TSEQ, CEMB, CEMB);
}

// Round 12
// 132.679 us; speedup vs baseline: 1.3484x; 1.0074x over previous
//
#include <hip/hip_runtime.h>
#include <hip/hip_bf16.h>

#define NHEAD 12
#define TSEQ 2048
#define CEMB 768
#define DHEAD 64
#define NBATCH 4

typedef __attribute__((ext_vector_type(8))) short bf16x8;
typedef __attribute__((ext_vector_type(4))) float f32x4;

__device__ __forceinline__ ushort f2bf(float f) {
  union { float f; unsigned u; } v; v.f = f;
  unsigned u = v.u;
  u += 0x7FFFu + ((u >> 16) & 1u);   // RNE to bf16
  return (ushort)(u >> 16);
}

// packed f32x2 -> bf16x2 (1 inst, RNE) — T12 primitive
__device__ __forceinline__ unsigned cvt_pk_bf16(float lo, float hi) {
  unsigned r;
  asm("v_cvt_pk_bf16_f32 %0, %1, %2" : "=v"(r) : "v"(lo), "v"(hi));
  return r;
}

// raw v_exp_f32: D = 2^S0 (scores pre-scaled to log2 domain)
__device__ __forceinline__ float exp2_raw(float x) {
  float r;
  asm("v_exp_f32 %0, %1" : "=v"(r) : "v"(x));
  return r;
}

// ---------- fused prep: cast x -> bf16, transpose+cast Wa and Wo ----------
__global__ __launch_bounds__(256)
void prep(const float* __restrict__ x, ushort* __restrict__ xb,
          const float* __restrict__ Wa, ushort* __restrict__ WaT,
          const float* __restrict__ Wo, ushort* __restrict__ WoT)
{
  __shared__ float tile[32][33];
  const int bid = blockIdx.x, t = threadIdx.x;
  if (bid < 3072) {
    int i = (bid * 256 + t) * 8;
    float4 v0 = *(const float4*)(x + i);
    float4 v1 = *(const float4*)(x + i + 4);
    bf16x8 wv;
    wv[0] = (short)f2bf(v0.x); wv[1] = (short)f2bf(v0.y);
    wv[2] = (short)f2bf(v0.z); wv[3] = (short)f2bf(v0.w);
    wv[4] = (short)f2bf(v1.x); wv[5] = (short)f2bf(v1.y);
    wv[6] = (short)f2bf(v1.z); wv[7] = (short)f2bf(v1.w);
    *(bf16x8*)(xb + i) = wv;
    return;
  }
  const int b2 = bid - 3072;
  const int bx = b2 % 96, by = b2 / 96;
  const int tx = t & 31, ty = t >> 5;         // (32,8)
  const float* src; ushort* dst; int C, c0;
  if (bx < 72) { src = Wa; dst = WaT; C = 3 * CEMB; c0 = bx * 32; }
  else         { src = Wo; dst = WoT; C = CEMB;     c0 = (bx - 72) * 32; }
  const int r0 = by * 32;
#pragma unroll
  for (int j = 0; j < 4; ++j)
    tile[ty + j * 8][tx] = src[(size_t)(r0 + ty + j * 8) * C + c0 + tx];
  __syncthreads();
#pragma unroll
  for (int j = 0; j < 4; ++j)
    dst[(size_t)(c0 + ty + j * 8) * CEMB + r0 + tx] = f2bf(tile[tx][ty + j * 8]);
}

// ---------- bf16 MFMA GEMM (m97 + 2-phase dbuf): C = A[M][K] * BT[N][K]^T + bias ----------
// EPI=1: q/k scatter to [B,H,T,D] (q pre-scaled by log2e/8); v written DIRECTLY to
// vT [B,H,D,T] (the 4 acc elements are 4 consecutive tokens -> contiguous 8B store).
template<int EPI>
__global__ __launch_bounds__(256)
void gemm_bf16(const ushort* __restrict__ A, const ushort* __restrict__ BT,
               const float* __restrict__ bias, float* __restrict__ outF,
               ushort* __restrict__ qd, ushort* __restrict__ kd, ushort* __restrict__ vd,
               int M, int N, int K)
{
  __shared__ __align__(16) char smem[32768];   // buf p: As @ p*16384, Bs @ +8192
  const int t = threadIdx.x;
  const int lane = t & 63, wv = t >> 6;
  const int cc = lane & 15, gg = lane >> 4;
  const int m0 = blockIdx.y * 128, n0 = blockIdx.x * 128;
  const int wm = (wv >> 1) * 64, wn = (wv & 1) * 64;

  const int o0 = wv * 1024 + lane * 16;
  const int o1 = o0 + 4096;
  const int r0s = o0 >> 6, s0s = (o0 >> 4) & 3;
  const int r1s = o1 >> 6, s1s = (o1 >> 4) & 3;
  const size_t Kb = (size_t)K * 2;
  const char* a0p = (const char*)A  + (size_t)(m0 + r0s) * Kb + ((s0s ^ ((r0s >> 1) & 3)) << 4);
  const char* a1p = (const char*)A  + (size_t)(m0 + r1s) * Kb + ((s1s ^ ((r1s >> 1) & 3)) << 4);
  const char* b0p = (const char*)BT + (size_t)(n0 + r0s) * Kb + ((s0s ^ ((r0s >> 1) & 3)) << 4);
  const char* b1p = (const char*)BT + (size_t)(n0 + r1s) * Kb + ((s1s ^ ((r1s >> 1) & 3)) << 4);

  auto stage_g = [&](int p, int kb) {
    char* As = smem + p * 16384;
    char* Bs = As + 8192;
    __builtin_amdgcn_global_load_lds(
        (const __attribute__((address_space(1))) unsigned*)(a0p + kb),
        (__attribute__((address_space(3))) unsigned*)(As + wv * 1024), 16, 0, 0);
    __builtin_amdgcn_global_load_lds(
        (const __attribute__((address_space(1))) unsigned*)(a1p + kb),
        (__attribute__((address_space(3))) unsigned*)(As + wv * 1024 + 4096), 16, 0, 0);
    __builtin_amdgcn_global_load_lds(
        (const __attribute__((address_space(1))) unsigned*)(b0p + kb),
        (__attribute__((address_space(3))) unsigned*)(Bs + wv * 1024), 16, 0, 0);
    __builtin_amdgcn_global_load_lds(
        (const __attribute__((address_space(1))) unsigned*)(b1p + kb),
        (__attribute__((address_space(3))) unsigned*)(Bs + wv * 1024 + 4096), 16, 0, 0);
  };

  f32x4 acc[4][4];
#pragma unroll
  for (int i = 0; i < 4; ++i)
#pragma unroll
    for (int j = 0; j < 4; ++j) acc[i][j] = (f32x4){0.f, 0.f, 0.f, 0.f};

  const int KB = K * 2;
  stage_g(0, 0);
  asm volatile("s_waitcnt vmcnt(0)" ::: "memory");
  __syncthreads();
  int p = 0;
  for (int kb = 0; kb < KB; kb += 64) {
    if (kb + 64 < KB) stage_g(p ^ 1, kb + 64);   // prefetch next tile (overlaps compute)
    const char* As = smem + p * 16384;
    const char* Bs = As + 8192;
    bf16x8 fa[4], fb[4];
#pragma unroll
    for (int i = 0; i < 4; ++i) {
      const int r = wm + i * 16 + cc;
      fa[i] = *(const bf16x8*)(As + r * 64 + ((gg ^ ((r >> 1) & 3)) << 4));
    }
#pragma unroll
    for (int j = 0; j < 4; ++j) {
      const int r = wn + j * 16 + cc;
      fb[j] = *(const bf16x8*)(Bs + r * 64 + ((gg ^ ((r >> 1) & 3)) << 4));
    }
    __builtin_amdgcn_s_setprio(1);
#pragma unroll
    for (int i = 0; i < 4; ++i)
#pragma unroll
      for (int j = 0; j < 4; ++j)
        acc[i][j] = __builtin_amdgcn_mfma_f32_16x16x32_bf16(fa[i], fb[j], acc[i][j], 0, 0, 0);
    __builtin_amdgcn_s_setprio(0);
    asm volatile("s_waitcnt vmcnt(0)" ::: "memory");   // next tile's stage landed
    __syncthreads();                                   // all waves done reading buf p
    p ^= 1;
  }

#pragma unroll
  for (int i = 0; i < 4; ++i) {
#pragma unroll
    for (int j = 0; j < 4; ++j) {
      int gm0 = m0 + wm + i * 16 + gg * 4;
      int gn  = n0 + wn + j * 16 + cc;
      float bv = bias[gn];
      if (EPI == 0) {
#pragma unroll
        for (int e = 0; e < 4; ++e)
          outF[(size_t)(gm0 + e) * N + gn] = acc[i][j][e] + bv;
      } else {
        int which = gn / CEMB;
        int r = gn - which * CEMB;
        int hh = r >> 6, dd = r & 63;
        int tt0 = gm0 & (TSEQ - 1), bb = gm0 >> 11;   // 4-aligned: same bb for e=0..3
        if (which == 2) {
          // v -> vT [B,H,D,T]: 4 consecutive tokens contiguous, one 8B store
          ushort* dstv = vd + ((size_t)((bb * NHEAD + hh) * DHEAD + dd)) * TSEQ + tt0;
          uint2 pw;
          pw.x = cvt_pk_bf16(acc[i][j][0] + bv, acc[i][j][1] + bv);
          pw.y = cvt_pk_bf16(acc[i][j][2] + bv, acc[i][j][3] + bv);
          *(uint2*)dstv = pw;
        } else {
          ushort* dst = which == 0 ? qd : kd;
          // q scale: 1/sqrt(D) * log2(e) — softmax computed with exp2
          float sc = (which == 0) ? 0.125f * 1.4426950408889634f : 1.0f;
#pragma unroll
          for (int e = 0; e < 4; ++e)
            dst[(size_t)((bb * NHEAD + hh) * TSEQ + tt0 + e) * DHEAD + dd] =
                f2bf((acc[i][j][e] + bv) * sc);
        }
      }
    }
  }
}

// ---------- flash attention (pipelined PV: PV(kt-1) overlaps softmax(kt)) ----------
// 1-D grid 768; decode maps all 16 bx-blocks of a head onto ONE XCD (T1).
// Block bx handles q-tiles bx and NT-1-bx (balanced, NT+1 key-tiles/wave).
// Buffers: K(kt+1) staged into K[p^1]; V(kt) staged into V[p] (read next iter from
// V[p^1]); P double-buffered per wave (write P[p], read P[p^1]). One vmcnt(0)+barrier
// per iteration orders everything — the old mid-tile lds_fence serial point is gone,
// and the PV MFMAs execute while softmax(kt) runs on the VALU pipe.
// R10 lesson kept: V must be LDS-staged (direct global vT reads are a 16-line scatter).
// Softmax in exp2 domain (Q pre-scaled by log2e/8), defer-max THR = 8*log2e (rare
// rescale is the only o-dependency on the in-flight PV).
__global__ __launch_bounds__(256)
void attn_fwd(const ushort* __restrict__ qg, const ushort* __restrict__ kg,
              const ushort* __restrict__ vTg, ushort* __restrict__ ybb)
{
  // LDS: K[2] @ 0 (2 x 8KB, swizzled), V[2] @ 16384, P @ 32768 (4 waves x 2 bufs x 2KB)
  __shared__ __align__(16) char smem[49152];
  const int t = threadIdx.x, lane = t & 63, w = t >> 6;
  const int cc = lane & 15, gg = lane >> 4;
  const int NT = TSEQ / 64;
  const int L = blockIdx.x;
  const int r9 = L >> 3;
  const int bx = r9 & 15;
  const int bh = (L & 7) + 8 * (r9 >> 4);     // same bh -> same XCD slot
  const int b = bh / NHEAD, h = bh - b * NHEAD;

  const char* Kg = (const char*)(kg + (size_t)bh * TSEQ * DHEAD);   // [T][64], 128B rows
  const char* Vg = (const char*)(vTg + (size_t)bh * TSEQ * DHEAD);  // [64][T], 4096B rows

  const int srow = lane >> 3;                        // row&7 within 8-row chunk
  const int ssw  = ((lane & 7) * 16) ^ (srow << 4);  // pre-swizzled source colbyte

  ushort* Pw = (ushort*)(smem + 32768 + w * 4096);   // wave-private, 2 bufs x 1024 ushorts
  const int sw8 = (cc & 7) << 3;

  auto stageK = [&](int pb, int kt) {
#pragma unroll
    for (int i = 0; i < 2; ++i) {
      const int c = w * 2 + i;
      const char* gk = Kg + (size_t)(kt * 64 + c * 8 + srow) * 128 + ssw;
      __builtin_amdgcn_global_load_lds(
          (const __attribute__((address_space(1))) unsigned*)gk,
          (__attribute__((address_space(3))) unsigned*)(smem + pb * 8192 + c * 1024),
          16, 0, 0);
    }
  };
  auto stageV = [&](int pb, int kt) {
#pragma unroll
    for (int i = 0; i < 2; ++i) {
      const int c = w * 2 + i;
      const char* gv = Vg + (size_t)(c * 8 + srow) * (TSEQ * 2) + (size_t)kt * 128 + ssw;
      __builtin_amdgcn_global_load_lds(
          (const __attribute__((address_space(1))) unsigned*)gv,
          (__attribute__((address_space(3))) unsigned*)(smem + 16384 + pb * 8192 + c * 1024),
          16, 0, 0);
    }
  };

  int p = 0;
  for (int pass = 0; pass < 2; ++pass) {
    const int qt = pass ? (NT - 1 - bx) : bx;
    const int qrow0 = qt * 64 + w * 16;

    const ushort* Qp = qg + ((size_t)bh * TSEQ + qrow0) * DHEAD;
    bf16x8 fq0 = *(const bf16x8*)(Qp + cc * DHEAD + 8 * gg);
    bf16x8 fq1 = *(const bf16x8*)(Qp + cc * DHEAD + 32 + 8 * gg);

    f32x4 o[4];   // O^T: o[dt][e] = O^T[d = dt*16 + gg*4 + e, q = cc]
#pragma unroll
    for (int i = 0; i < 4; ++i) o[i] = (f32x4){0.f, 0.f, 0.f, 0.f};
    float m = -1e30f, l = 0.f;

    stageK(p, 0);
    asm volatile("s_waitcnt vmcnt(0)" ::: "memory");
    __syncthreads();

    for (int kt = 0; kt <= qt; ++kt) {
      if (kt < qt) stageK(p ^ 1, kt + 1);   // K for next iter
      stageV(p, kt);                        // V consumed next iter (PV(kt))

      // ---- QK(kt) from K[p] ----
      const char* Kl = smem + p * 8192;
      f32x4 st[4];   // st[ct][e] = S^T[key = 16ct + 4gg + e, q = cc]  (log2 domain)
#pragma unroll
      for (int ct = 0; ct < 4; ++ct) st[ct] = (f32x4){0.f, 0.f, 0.f, 0.f};
      __builtin_amdgcn_s_setprio(1);
#pragma unroll
      for (int ct = 0; ct < 4; ++ct) {
        const int r = ct * 16 + cc;
        const char* kb = Kl + r * 128;
        bf16x8 fk0 = *(const bf16x8*)(kb + ((gg * 16) ^ ((r & 7) << 4)));
        bf16x8 fk1 = *(const bf16x8*)(kb + ((64 + gg * 16) ^ ((r & 7) << 4)));
        st[ct] = __builtin_amdgcn_mfma_f32_16x16x32_bf16(fk0, fq0, st[ct], 0, 0, 0);
        st[ct] = __builtin_amdgcn_mfma_f32_16x16x32_bf16(fk1, fq1, st[ct], 0, 0, 0);
      }

      // ---- PV(kt-1) from V[p^1], P[p^1] — independent of QK; overlaps softmax ----
      if (kt > 0) {
        const char* Vprev = smem + 16384 + (p ^ 1) * 8192;
        const ushort* Pprev = Pw + (p ^ 1) * 1024;
#pragma unroll
        for (int kc = 0; kc < 2; ++kc) {
          bf16x8 pb = *(const bf16x8*)&Pprev[cc * 64 + ((kc * 32 + 8 * gg) ^ sw8)];
#pragma unroll
          for (int dt = 0; dt < 4; ++dt) {
            const int rd = dt * 16 + cc;
            bf16x8 fv = *(const bf16x8*)(Vprev + rd * 128 + ((kc * 64 + gg * 16) ^ ((rd & 7) << 4)));
            o[dt] = __builtin_amdgcn_mfma_f32_16x16x32_bf16(fv, pb, o[dt], 0, 0, 0);
          }
        }
      }
      __builtin_amdgcn_s_setprio(0);

      // ---- softmax(kt) ----
      if (kt == qt) {   // causal mask on the diagonal tile
#pragma unroll
        for (int ct = 0; ct < 4; ++ct)
#pragma unroll
          for (int e = 0; e < 4; ++e)
            if (ct * 16 + gg * 4 + e > w * 16 + cc) st[ct][e] = -1e30f;
      }
      float ml = st[0][0];
#pragma unroll
      for (int ct = 0; ct < 4; ++ct)
#pragma unroll
        for (int e = 0; e < 4; ++e) ml = fmaxf(ml, st[ct][e]);
      ml = fmaxf(ml, __shfl_xor(ml, 16, 64));
      ml = fmaxf(ml, __shfl_xor(ml, 32, 64));
      float mn = m;
      if (!__all(ml - m <= 11.54f)) {   // defer-max (T13); rare — only path that waits on PV
        mn = fmaxf(m, ml);
        float al = exp2_raw(m - mn);
#pragma unroll
        for (int dt = 0; dt < 4; ++dt)
#pragma unroll
          for (int e = 0; e < 4; ++e) o[dt][e] *= al;
        l *= al;
        m = mn;
      }
      float ps = 0.f;
#pragma unroll
      for (int ct = 0; ct < 4; ++ct)
#pragma unroll
        for (int e = 0; e < 4; ++e) { float pp = exp2_raw(st[ct][e] - mn); st[ct][e] = pp; ps += pp; }
#pragma unroll
      for (int ct = 0; ct < 4; ++ct) {
        uint2 pw;
        pw.x = cvt_pk_bf16(st[ct][0], st[ct][1]);
        pw.y = cvt_pk_bf16(st[ct][2], st[ct][3]);
        *(uint2*)&Pw[p * 1024 + cc * 64 + ((ct * 16 + gg * 4) ^ sw8)] = pw;
      }
      ps += __shfl_xor(ps, 16, 64);
      ps += __shfl_xor(ps, 32, 64);
      l += ps;

      asm volatile("s_waitcnt vmcnt(0)" ::: "memory");   // K(kt+1) + V(kt) landed
      __syncthreads();                                   // P(kt) writes + buf reads ordered
      p ^= 1;
    }

    // ---- epilogue: PV(qt) (parity of iter qt is p^1 after the final flip) ----
    {
      const char* Vlast = smem + 16384 + (p ^ 1) * 8192;
      const ushort* Plast = Pw + (p ^ 1) * 1024;
#pragma unroll
      for (int kc = 0; kc < 2; ++kc) {
        bf16x8 pb = *(const bf16x8*)&Plast[cc * 64 + ((kc * 32 + 8 * gg) ^ sw8)];
#pragma unroll
        for (int dt = 0; dt < 4; ++dt) {
          const int rd = dt * 16 + cc;
          bf16x8 fv = *(const bf16x8*)(Vlast + rd * 128 + ((kc * 64 + gg * 16) ^ ((rd & 7) << 4)));
          o[dt] = __builtin_amdgcn_mfma_f32_16x16x32_bf16(fv, pb, o[dt], 0, 0, 0);
        }
      }
    }

    float inv = 1.0f / l;
    ushort* yrow = ybb + (size_t)(b * TSEQ + qrow0 + cc) * CEMB + h * DHEAD;
#pragma unroll
    for (int dt = 0; dt < 4; ++dt) {
      uint2 pw;
      pw.x = cvt_pk_bf16(o[dt][0] * inv, o[dt][1] * inv);
      pw.y = cvt_pk_bf16(o[dt][2] * inv, o[dt][3] * inv);
      *(uint2*)(yrow + dt * 16 + gg * 4) = pw;
    }
  }
}

extern "C" void kernel_launch(void* const* d_in, const int* in_sizes, int n_in,
                              void* d_out, int out_size, void* d_ws, size_t ws_size,
                              hipStream_t stream)
{
  (void)in_sizes; (void)n_in; (void)out_size; (void)ws_size;
  const float* x  = (const float*)d_in[0];
  const float* Wa = (const float*)d_in[1];
  const float* ba = (const float*)d_in[2];
  const float* Wo = (const float*)d_in[3];
  const float* bo = (const float*)d_in[4];
  float* out = (float*)d_out;

  char* p = (char*)d_ws;
  ushort* WaT  = (ushort*)p; p += (size_t)3 * CEMB * CEMB * 2;               // [2304][768] bf16
  ushort* WoT  = (ushort*)p; p += (size_t)CEMB * CEMB * 2;                   // [768][768] bf16
  ushort* xb   = (ushort*)p; p += (size_t)NBATCH * TSEQ * CEMB * 2;          // x bf16 [B*T][C]
  ushort* qb   = (ushort*)p; p += (size_t)NBATCH * NHEAD * TSEQ * DHEAD * 2; // [B,H,T,D]
  ushort* kb   = (ushort*)p; p += (size_t)NBATCH * NHEAD * TSEQ * DHEAD * 2;
  ushort* vT   = (ushort*)p; p += (size_t)NBATCH * NHEAD * TSEQ * DHEAD * 2; // [B,H,D,T] (direct)
  ushort* yb   = (ushort*)p; p += (size_t)NBATCH * TSEQ * CEMB * 2;          // attn out bf16

  prep<<<3072 + 96 * 24, 256, 0, stream>>>(x, xb, Wa, WaT, Wo, WoT);
  gemm_bf16<1><<<dim3(3 * CEMB / 128, NBATCH * TSEQ / 128), 256, 0, stream>>>(
      xb, WaT, ba, nullptr, qb, kb, vT, NBATCH * TSEQ, 3 * CEMB, CEMB);
  attn_fwd<<<dim3(TSEQ / 128 * NBATCH * NHEAD), 256, 0, stream>>>(qb, kb, vT, yb);
  gemm_bf16<0><<<dim3(CEMB / 128, NBATCH * TSEQ / 128), 256, 0, stream>>>(
      yb, WoT, bo, out, nullptr, nullptr, nullptr, NBATCH * TSEQ, CEMB, CEMB);
}

// Round 13
// 132.363 us; speedup vs baseline: 1.3517x; 1.0024x over previous
//
#include <hip/hip_runtime.h>
#include <hip/hip_bf16.h>

#define NHEAD 12
#define TSEQ 2048
#define CEMB 768
#define DHEAD 64
#define NBATCH 4

typedef __attribute__((ext_vector_type(8))) short bf16x8;
typedef __attribute__((ext_vector_type(4))) float f32x4;

__device__ __forceinline__ ushort f2bf(float f) {
  union { float f; unsigned u; } v; v.f = f;
  unsigned u = v.u;
  u += 0x7FFFu + ((u >> 16) & 1u);   // RNE to bf16
  return (ushort)(u >> 16);
}

// packed f32x2 -> bf16x2 (1 inst, RNE) — T12 primitive
__device__ __forceinline__ unsigned cvt_pk_bf16(float lo, float hi) {
  unsigned r;
  asm("v_cvt_pk_bf16_f32 %0, %1, %2" : "=v"(r) : "v"(lo), "v"(hi));
  return r;
}

// raw v_exp_f32: D = 2^S0 (scores pre-scaled to log2 domain)
__device__ __forceinline__ float exp2_raw(float x) {
  float r;
  asm("v_exp_f32 %0, %1" : "=v"(r) : "v"(x));
  return r;
}

// ---------- fused prep: cast x -> bf16, transpose+cast Wa and Wo ----------
__global__ __launch_bounds__(256)
void prep(const float* __restrict__ x, ushort* __restrict__ xb,
          const float* __restrict__ Wa, ushort* __restrict__ WaT,
          const float* __restrict__ Wo, ushort* __restrict__ WoT)
{
  __shared__ float tile[32][33];
  const int bid = blockIdx.x, t = threadIdx.x;
  if (bid < 3072) {
    int i = (bid * 256 + t) * 8;
    float4 v0 = *(const float4*)(x + i);
    float4 v1 = *(const float4*)(x + i + 4);
    bf16x8 wv;
    wv[0] = (short)f2bf(v0.x); wv[1] = (short)f2bf(v0.y);
    wv[2] = (short)f2bf(v0.z); wv[3] = (short)f2bf(v0.w);
    wv[4] = (short)f2bf(v1.x); wv[5] = (short)f2bf(v1.y);
    wv[6] = (short)f2bf(v1.z); wv[7] = (short)f2bf(v1.w);
    *(bf16x8*)(xb + i) = wv;
    return;
  }
  const int b2 = bid - 3072;
  const int bx = b2 % 96, by = b2 / 96;
  const int tx = t & 31, ty = t >> 5;         // (32,8)
  const float* src; ushort* dst; int C, c0;
  if (bx < 72) { src = Wa; dst = WaT; C = 3 * CEMB; c0 = bx * 32; }
  else         { src = Wo; dst = WoT; C = CEMB;     c0 = (bx - 72) * 32; }
  const int r0 = by * 32;
#pragma unroll
  for (int j = 0; j < 4; ++j)
    tile[ty + j * 8][tx] = src[(size_t)(r0 + ty + j * 8) * C + c0 + tx];
  __syncthreads();
#pragma unroll
  for (int j = 0; j < 4; ++j)
    dst[(size_t)(c0 + ty + j * 8) * CEMB + r0 + tx] = f2bf(tile[tx][ty + j * 8]);
}

// ---------- bf16 MFMA GEMM (m97 + 2-phase dbuf): C = A[M][K] * BT[N][K]^T + bias ----------
// EPI=1: q/k scatter to [B,H,T,D] (q pre-scaled by log2e/8); v written DIRECTLY to
// vT [B,H,D,T] (the 4 acc elements are 4 consecutive tokens -> contiguous 8B store).
template<int EPI>
__global__ __launch_bounds__(256)
void gemm_bf16(const ushort* __restrict__ A, const ushort* __restrict__ BT,
               const float* __restrict__ bias, float* __restrict__ outF,
               ushort* __restrict__ qd, ushort* __restrict__ kd, ushort* __restrict__ vd,
               int M, int N, int K)
{
  __shared__ __align__(16) char smem[32768];   // buf p: As @ p*16384, Bs @ +8192
  const int t = threadIdx.x;
  const int lane = t & 63, wv = t >> 6;
  const int cc = lane & 15, gg = lane >> 4;
  const int m0 = blockIdx.y * 128, n0 = blockIdx.x * 128;
  const int wm = (wv >> 1) * 64, wn = (wv & 1) * 64;

  const int o0 = wv * 1024 + lane * 16;
  const int o1 = o0 + 4096;
  const int r0s = o0 >> 6, s0s = (o0 >> 4) & 3;
  const int r1s = o1 >> 6, s1s = (o1 >> 4) & 3;
  const size_t Kb = (size_t)K * 2;
  const char* a0p = (const char*)A  + (size_t)(m0 + r0s) * Kb + ((s0s ^ ((r0s >> 1) & 3)) << 4);
  const char* a1p = (const char*)A  + (size_t)(m0 + r1s) * Kb + ((s1s ^ ((r1s >> 1) & 3)) << 4);
  const char* b0p = (const char*)BT + (size_t)(n0 + r0s) * Kb + ((s0s ^ ((r0s >> 1) & 3)) << 4);
  const char* b1p = (const char*)BT + (size_t)(n0 + r1s) * Kb + ((s1s ^ ((r1s >> 1) & 3)) << 4);

  auto stage_g = [&](int p, int kb) {
    char* As = smem + p * 16384;
    char* Bs = As + 8192;
    __builtin_amdgcn_global_load_lds(
        (const __attribute__((address_space(1))) unsigned*)(a0p + kb),
        (__attribute__((address_space(3))) unsigned*)(As + wv * 1024), 16, 0, 0);
    __builtin_amdgcn_global_load_lds(
        (const __attribute__((address_space(1))) unsigned*)(a1p + kb),
        (__attribute__((address_space(3))) unsigned*)(As + wv * 1024 + 4096), 16, 0, 0);
    __builtin_amdgcn_global_load_lds(
        (const __attribute__((address_space(1))) unsigned*)(b0p + kb),
        (__attribute__((address_space(3))) unsigned*)(Bs + wv * 1024), 16, 0, 0);
    __builtin_amdgcn_global_load_lds(
        (const __attribute__((address_space(1))) unsigned*)(b1p + kb),
        (__attribute__((address_space(3))) unsigned*)(Bs + wv * 1024 + 4096), 16, 0, 0);
  };

  f32x4 acc[4][4];
#pragma unroll
  for (int i = 0; i < 4; ++i)
#pragma unroll
    for (int j = 0; j < 4; ++j) acc[i][j] = (f32x4){0.f, 0.f, 0.f, 0.f};

  const int KB = K * 2;
  stage_g(0, 0);
  asm volatile("s_waitcnt vmcnt(0)" ::: "memory");
  __syncthreads();
  int p = 0;
  for (int kb = 0; kb < KB; kb += 64) {
    if (kb + 64 < KB) stage_g(p ^ 1, kb + 64);   // prefetch next tile (overlaps compute)
    const char* As = smem + p * 16384;
    const char* Bs = As + 8192;
    bf16x8 fa[4], fb[4];
#pragma unroll
    for (int i = 0; i < 4; ++i) {
      const int r = wm + i * 16 + cc;
      fa[i] = *(const bf16x8*)(As + r * 64 + ((gg ^ ((r >> 1) & 3)) << 4));
    }
#pragma unroll
    for (int j = 0; j < 4; ++j) {
      const int r = wn + j * 16 + cc;
      fb[j] = *(const bf16x8*)(Bs + r * 64 + ((gg ^ ((r >> 1) & 3)) << 4));
    }
    __builtin_amdgcn_s_setprio(1);
#pragma unroll
    for (int i = 0; i < 4; ++i)
#pragma unroll
      for (int j = 0; j < 4; ++j)
        acc[i][j] = __builtin_amdgcn_mfma_f32_16x16x32_bf16(fa[i], fb[j], acc[i][j], 0, 0, 0);
    __builtin_amdgcn_s_setprio(0);
    asm volatile("s_waitcnt vmcnt(0)" ::: "memory");   // next tile's stage landed
    __syncthreads();                                   // all waves done reading buf p
    p ^= 1;
  }

#pragma unroll
  for (int i = 0; i < 4; ++i) {
#pragma unroll
    for (int j = 0; j < 4; ++j) {
      int gm0 = m0 + wm + i * 16 + gg * 4;
      int gn  = n0 + wn + j * 16 + cc;
      float bv = bias[gn];
      if (EPI == 0) {
#pragma unroll
        for (int e = 0; e < 4; ++e)
          outF[(size_t)(gm0 + e) * N + gn] = acc[i][j][e] + bv;
      } else {
        int which = gn / CEMB;
        int r = gn - which * CEMB;
        int hh = r >> 6, dd = r & 63;
        int tt0 = gm0 & (TSEQ - 1), bb = gm0 >> 11;   // 4-aligned: same bb for e=0..3
        if (which == 2) {
          // v -> vT [B,H,D,T]: 4 consecutive tokens contiguous, one 8B store
          ushort* dstv = vd + ((size_t)((bb * NHEAD + hh) * DHEAD + dd)) * TSEQ + tt0;
          uint2 pw;
          pw.x = cvt_pk_bf16(acc[i][j][0] + bv, acc[i][j][1] + bv);
          pw.y = cvt_pk_bf16(acc[i][j][2] + bv, acc[i][j][3] + bv);
          *(uint2*)dstv = pw;
        } else {
          ushort* dst = which == 0 ? qd : kd;
          // q scale: 1/sqrt(D) * log2(e) — softmax computed with exp2
          float sc = (which == 0) ? 0.125f * 1.4426950408889634f : 1.0f;
#pragma unroll
          for (int e = 0; e < 4; ++e)
            dst[(size_t)((bb * NHEAD + hh) * TSEQ + tt0 + e) * DHEAD + dd] =
                f2bf((acc[i][j][e] + bv) * sc);
        }
      }
    }
  }
}

// ---------- flash attention (pipelined PV + eager-exp softmax + MFMA l-sum) ----------
// 1-D grid 768; decode maps all 16 bx-blocks of a head onto ONE XCD (T1).
// Block bx handles q-tiles bx and NT-1-bx (balanced, NT+1 key-tiles/wave).
// Buffers: K(kt+1)->K[p^1]; V(kt)->V[p] (read next iter); P dbuf per wave.
// EAGER EXP: pp = exp2(st - m_running) issued immediately after QK (no wait on the
// cross-lane max). Max + 2-shfl reduce runs off the critical path; if the tile max
// exceeds m+THR (rare), fix up by scaling pp/o/l by al = 2^(m-mn) and re-storing P
// (exact: exp2(st-mn) = pp*al). m starts at 0 (log2-domain scores are O(10);
// f32/bf16 absorb the interim 2^40 magnitudes).
// l-sum via MFMA: l4 = mfma(ones, P) on the 17%-busy matrix pipe replaces
// 16 v_adds + 2 shfl per tile.
// R10 lesson kept: V must be LDS-staged (direct global vT reads are a 16-line scatter).
__global__ __launch_bounds__(256)
void attn_fwd(const ushort* __restrict__ qg, const ushort* __restrict__ kg,
              const ushort* __restrict__ vTg, ushort* __restrict__ ybb)
{
  // LDS: K[2] @ 0 (2 x 8KB, swizzled), V[2] @ 16384, P @ 32768 (4 waves x 2 bufs x 2KB)
  __shared__ __align__(16) char smem[49152];
  const int t = threadIdx.x, lane = t & 63, w = t >> 6;
  const int cc = lane & 15, gg = lane >> 4;
  const int NT = TSEQ / 64;
  const int L = blockIdx.x;
  const int r9 = L >> 3;
  const int bx = r9 & 15;
  const int bh = (L & 7) + 8 * (r9 >> 4);     // same bh -> same XCD slot
  const int b = bh / NHEAD, h = bh - b * NHEAD;

  const char* Kg = (const char*)(kg + (size_t)bh * TSEQ * DHEAD);   // [T][64], 128B rows
  const char* Vg = (const char*)(vTg + (size_t)bh * TSEQ * DHEAD);  // [64][T], 4096B rows

  const int srow = lane >> 3;                        // row&7 within 8-row chunk
  const int ssw  = ((lane & 7) * 16) ^ (srow << 4);  // pre-swizzled source colbyte

  ushort* Pw = (ushort*)(smem + 32768 + w * 4096);   // wave-private, 2 bufs x 1024 ushorts
  const int sw8 = (cc & 7) << 3;

  bf16x8 ones;
#pragma unroll
  for (int i = 0; i < 8; ++i) ones[i] = (short)0x3F80;   // bf16 1.0

  auto stageK = [&](int pb, int kt) {
#pragma unroll
    for (int i = 0; i < 2; ++i) {
      const int c = w * 2 + i;
      const char* gk = Kg + (size_t)(kt * 64 + c * 8 + srow) * 128 + ssw;
      __builtin_amdgcn_global_load_lds(
          (const __attribute__((address_space(1))) unsigned*)gk,
          (__attribute__((address_space(3))) unsigned*)(smem + pb * 8192 + c * 1024),
          16, 0, 0);
    }
  };
  auto stageV = [&](int pb, int kt) {
#pragma unroll
    for (int i = 0; i < 2; ++i) {
      const int c = w * 2 + i;
      const char* gv = Vg + (size_t)(c * 8 + srow) * (TSEQ * 2) + (size_t)kt * 128 + ssw;
      __builtin_amdgcn_global_load_lds(
          (const __attribute__((address_space(1))) unsigned*)gv,
          (__attribute__((address_space(3))) unsigned*)(smem + 16384 + pb * 8192 + c * 1024),
          16, 0, 0);
    }
  };

  int p = 0;
  for (int pass = 0; pass < 2; ++pass) {
    const int qt = pass ? (NT - 1 - bx) : bx;
    const int qrow0 = qt * 64 + w * 16;

    const ushort* Qp = qg + ((size_t)bh * TSEQ + qrow0) * DHEAD;
    bf16x8 fq0 = *(const bf16x8*)(Qp + cc * DHEAD + 8 * gg);
    bf16x8 fq1 = *(const bf16x8*)(Qp + cc * DHEAD + 32 + 8 * gg);

    f32x4 o[4];    // O^T: o[dt][e] = O^T[d = dt*16 + gg*4 + e, q = cc]
    f32x4 l4 = (f32x4){0.f, 0.f, 0.f, 0.f};   // MFMA-ones row-sum acc (all elems equal)
#pragma unroll
    for (int i = 0; i < 4; ++i) o[i] = (f32x4){0.f, 0.f, 0.f, 0.f};
    float m = 0.f;   // running max, log2 domain (eager-exp: start at 0, fix up as needed)

    stageK(p, 0);
    asm volatile("s_waitcnt vmcnt(0)" ::: "memory");
    __syncthreads();

    for (int kt = 0; kt <= qt; ++kt) {
      if (kt < qt) stageK(p ^ 1, kt + 1);   // K for next iter
      stageV(p, kt);                        // V consumed next iter (PV(kt))

      // ---- QK(kt) from K[p] ----
      const char* Kl = smem + p * 8192;
      f32x4 st[4];   // st[ct][e] = S^T[key = 16ct + 4gg + e, q = cc]  (log2 domain)
#pragma unroll
      for (int ct = 0; ct < 4; ++ct) st[ct] = (f32x4){0.f, 0.f, 0.f, 0.f};
      __builtin_amdgcn_s_setprio(1);
#pragma unroll
      for (int ct = 0; ct < 4; ++ct) {
        const int r = ct * 16 + cc;
        const char* kb = Kl + r * 128;
        bf16x8 fk0 = *(const bf16x8*)(kb + ((gg * 16) ^ ((r & 7) << 4)));
        bf16x8 fk1 = *(const bf16x8*)(kb + ((64 + gg * 16) ^ ((r & 7) << 4)));
        st[ct] = __builtin_amdgcn_mfma_f32_16x16x32_bf16(fk0, fq0, st[ct], 0, 0, 0);
        st[ct] = __builtin_amdgcn_mfma_f32_16x16x32_bf16(fk1, fq1, st[ct], 0, 0, 0);
      }

      // ---- PV(kt-1) + l-sum(kt-1) from V[p^1], P[p^1] — overlaps softmax ----
      if (kt > 0) {
        const char* Vprev = smem + 16384 + (p ^ 1) * 8192;
        const ushort* Pprev = Pw + (p ^ 1) * 1024;
#pragma unroll
        for (int kc = 0; kc < 2; ++kc) {
          bf16x8 pb = *(const bf16x8*)&Pprev[cc * 64 + ((kc * 32 + 8 * gg) ^ sw8)];
          l4 = __builtin_amdgcn_mfma_f32_16x16x32_bf16(ones, pb, l4, 0, 0, 0);
#pragma unroll
          for (int dt = 0; dt < 4; ++dt) {
            const int rd = dt * 16 + cc;
            bf16x8 fv = *(const bf16x8*)(Vprev + rd * 128 + ((kc * 64 + gg * 16) ^ ((rd & 7) << 4)));
            o[dt] = __builtin_amdgcn_mfma_f32_16x16x32_bf16(fv, pb, o[dt], 0, 0, 0);
          }
        }
      }
      __builtin_amdgcn_s_setprio(0);

      // ---- eager softmax(kt): exp with running m, no cross-lane wait ----
      if (kt == qt) {   // causal mask on the diagonal tile
#pragma unroll
        for (int ct = 0; ct < 4; ++ct)
#pragma unroll
          for (int e = 0; e < 4; ++e)
            if (ct * 16 + gg * 4 + e > w * 16 + cc) st[ct][e] = -1e30f;
      }
      f32x4 pe[4];
#pragma unroll
      for (int ct = 0; ct < 4; ++ct)
#pragma unroll
        for (int e = 0; e < 4; ++e) pe[ct][e] = exp2_raw(st[ct][e] - m);
#pragma unroll
      for (int ct = 0; ct < 4; ++ct) {
        uint2 pw;
        pw.x = cvt_pk_bf16(pe[ct][0], pe[ct][1]);
        pw.y = cvt_pk_bf16(pe[ct][2], pe[ct][3]);
        *(uint2*)&Pw[p * 1024 + cc * 64 + ((ct * 16 + gg * 4) ^ sw8)] = pw;
      }
      // off-critical-path max (max3-fused triples) + deferred check
      float ml = fmaxf(fmaxf(st[0][0], st[0][1]), st[0][2]);
      ml = fmaxf(fmaxf(ml, st[0][3]), fmaxf(st[1][0], st[1][1]));
      ml = fmaxf(fmaxf(ml, st[1][2]), fmaxf(st[1][3], st[2][0]));
      ml = fmaxf(fmaxf(ml, st[2][1]), fmaxf(st[2][2], st[2][3]));
      ml = fmaxf(fmaxf(ml, st[3][0]), fmaxf(st[3][1], st[3][2]));
      ml = fmaxf(ml, st[3][3]);
      ml = fmaxf(ml, __shfl_xor(ml, 16, 64));
      ml = fmaxf(ml, __shfl_xor(ml, 32, 64));
      if (!__all(ml - m <= 11.54f)) {   // rare fixup: rescale (no re-exp needed)
        float mn = fmaxf(m, ml);
        float al = exp2_raw(m - mn);
#pragma unroll
        for (int dt = 0; dt < 4; ++dt)
#pragma unroll
          for (int e = 0; e < 4; ++e) o[dt][e] *= al;
#pragma unroll
        for (int e = 0; e < 4; ++e) l4[e] *= al;
#pragma unroll
        for (int ct = 0; ct < 4; ++ct) {
#pragma unroll
          for (int e = 0; e < 4; ++e) pe[ct][e] *= al;
          uint2 pw;
          pw.x = cvt_pk_bf16(pe[ct][0], pe[ct][1]);
          pw.y = cvt_pk_bf16(pe[ct][2], pe[ct][3]);
          *(uint2*)&Pw[p * 1024 + cc * 64 + ((ct * 16 + gg * 4) ^ sw8)] = pw;
        }
        m = mn;
      }

      asm volatile("s_waitcnt vmcnt(0)" ::: "memory");   // K(kt+1) + V(kt) landed
      __syncthreads();                                   // P(kt) writes + buf reads ordered
      p ^= 1;
    }

    // ---- epilogue: PV(qt) + l-sum(qt) (parity p^1 after the final flip) ----
    {
      const char* Vlast = smem + 16384 + (p ^ 1) * 8192;
      const ushort* Plast = Pw + (p ^ 1) * 1024;
#pragma unroll
      for (int kc = 0; kc < 2; ++kc) {
        bf16x8 pb = *(const bf16x8*)&Plast[cc * 64 + ((kc * 32 + 8 * gg) ^ sw8)];
        l4 = __builtin_amdgcn_mfma_f32_16x16x32_bf16(ones, pb, l4, 0, 0, 0);
#pragma unroll
        for (int dt = 0; dt < 4; ++dt) {
          const int rd = dt * 16 + cc;
          bf16x8 fv = *(const bf16x8*)(Vlast + rd * 128 + ((kc * 64 + gg * 16) ^ ((rd & 7) << 4)));
          o[dt] = __builtin_amdgcn_mfma_f32_16x16x32_bf16(fv, pb, o[dt], 0, 0, 0);
        }
      }
    }

    float inv = 1.0f / l4[0];
    ushort* yrow = ybb + (size_t)(b * TSEQ + qrow0 + cc) * CEMB + h * DHEAD;
#pragma unroll
    for (int dt = 0; dt < 4; ++dt) {
      uint2 pw;
      pw.x = cvt_pk_bf16(o[dt][0] * inv, o[dt][1] * inv);
      pw.y = cvt_pk_bf16(o[dt][2] * inv, o[dt][3] * inv);
      *(uint2*)(yrow + dt * 16 + gg * 4) = pw;
    }
  }
}

extern "C" void kernel_launch(void* const* d_in, const int* in_sizes, int n_in,
                              void* d_out, int out_size, void* d_ws, size_t ws_size,
                              hipStream_t stream)
{
  (void)in_sizes; (void)n_in; (void)out_size; (void)ws_size;
  const float* x  = (const float*)d_in[0];
  const float* Wa = (const float*)d_in[1];
  const float* ba = (const float*)d_in[2];
  const float* Wo = (const float*)d_in[3];
  const float* bo = (const float*)d_in[4];
  float* out = (float*)d_out;

  char* p = (char*)d_ws;
  ushort* WaT  = (ushort*)p; p += (size_t)3 * CEMB * CEMB * 2;               // [2304][768] bf16
  ushort* WoT  = (ushort*)p; p += (size_t)CEMB * CEMB * 2;                   // [768][768] bf16
  ushort* xb   = (ushort*)p; p += (size_t)NBATCH * TSEQ * CEMB * 2;          // x bf16 [B*T][C]
  ushort* qb   = (ushort*)p; p += (size_t)NBATCH * NHEAD * TSEQ * DHEAD * 2; // [B,H,T,D]
  ushort* kb   = (ushort*)p; p += (size_t)NBATCH * NHEAD * TSEQ * DHEAD * 2;
  ushort* vT   = (ushort*)p; p += (size_t)NBATCH * NHEAD * TSEQ * DHEAD * 2; // [B,H,D,T] (direct)
  ushort* yb   = (ushort*)p; p += (size_t)NBATCH * TSEQ * CEMB * 2;          // attn out bf16

  prep<<<3072 + 96 * 24, 256, 0, stream>>>(x, xb, Wa, WaT, Wo, WoT);
  gemm_bf16<1><<<dim3(3 * CEMB / 128, NBATCH * TSEQ / 128), 256, 0, stream>>>(
      xb, WaT, ba, nullptr, qb, kb, vT, NBATCH * TSEQ, 3 * CEMB, CEMB);
  attn_fwd<<<dim3(TSEQ / 128 * NBATCH * NHEAD), 256, 0, stream>>>(qb, kb, vT, yb);
  gemm_bf16<0><<<dim3(CEMB / 128, NBATCH * TSEQ / 128), 256, 0, stream>>>(
      yb, WoT, bo, out, nullptr, nullptr, nullptr, NBATCH * TSEQ, CEMB, CEMB);
}